// Round 1
// baseline (1154.150 us; speedup 1.0000x reference)
//
#include <hip/hip_runtime.h>
#include <hip/hip_bf16.h>
#include <math.h>

// ---------------------------------------------------------------------------
// WindowAttention (Video-Swin style, self + mutual branch), MI355X / gfx950
// Pipeline:
//   prep_kernel : weight transposes -> bf16, rpb gather -> ws  (<1 MB ws)
//   attn_kernel : per-window fused QKV + self-attn + mutual-attn -> concat
//                 (concat [B,128,384] bf16 lives in d_out's bytes: exact fit)
//   proj_kernel : concat @ w_proj + b_proj -> d_out fp32, in-place-safe
// ---------------------------------------------------------------------------

#define SCALE_F 0.17677669529663687f  // 32^-0.5

// ws layout (bytes)
#define WS_WQKV_T   0u        // [576][192] bf16  (B[k][n] transposed: [col][k])
#define WS_WQKVM_T  221184u   // [576][192] bf16
#define WS_WPROJ_T  442368u   // [192][384] bf16  ([n][k])
#define WS_RPBG     589824u   // [6][128][128] f32 (bias gather resolved)
#define WS_NEEDED   983040u

typedef __bf16 bf16x8 __attribute__((ext_vector_type(8)));
typedef float  f32x4  __attribute__((ext_vector_type(4)));

#define MFMA(a, b, c) __builtin_amdgcn_mfma_f32_16x16x32_bf16((a), (b), (c), 0, 0, 0)

// ---------------------------------------------------------------------------
__global__ void prep_kernel(const float* __restrict__ w_qkv,
                            const float* __restrict__ w_qkvm,
                            const float* __restrict__ w_proj,
                            const float* __restrict__ rpb_table,
                            const int*   __restrict__ rel_idx,
                            char* __restrict__ ws) {
    int idx = blockIdx.x * 256 + threadIdx.x;
    if (idx < 110592) {                       // wqkv_t / wqkvm_t: [col][k]
        int col = idx / 192, k = idx - col * 192;
        ((__bf16*)(ws + WS_WQKV_T))[idx]  = (__bf16)w_qkv[k * 576 + col];
        ((__bf16*)(ws + WS_WQKVM_T))[idx] = (__bf16)w_qkvm[k * 576 + col];
    } else if (idx < 184320) {                // wproj_t: [n][k]
        int o = idx - 110592;
        int n = o / 384, k = o - n * 384;
        ((__bf16*)(ws + WS_WPROJ_T))[o] = (__bf16)w_proj[k * 192 + n];
    } else if (idx < 282624) {                // rpbg[h][i][j]
        int o = idx - 184320;
        int h = o / 16384, r = o - h * 16384;
        ((float*)(ws + WS_RPBG))[o] = rpb_table[rel_idx[r] * 6 + h];
    }
}

// ---------------------------------------------------------------------------
// One block per window. 256 threads = 4 waves; wave w owns query rows
// [32w, 32w+32). MFMA 16x16x32 bf16 layouts (HW-verified per guide):
//   A[m = lane&15][k = quad*8 + j]
//   B[k = quad*8 + j][n = lane&15]
//   D: col = lane&15, row = quad*4 + reg
__global__ __launch_bounds__(256, 1)
void attn_kernel(const float* __restrict__ x,
                 const float* __restrict__ mask,
                 const float* __restrict__ pos_bias,
                 const char*  __restrict__ ws,
                 __bf16* __restrict__ concat) {
    __shared__ alignas(16) __bf16 xw[128][200];  // x (then x+pb) bf16
    __shared__ alignas(16) __bf16 qh[128][40];   // Q head [token][dim]
    __shared__ alignas(16) __bf16 kh[128][40];   // K head [token][dim]
    __shared__ alignas(16) __bf16 vt[32][136];   // V head transposed [dim][token]
    __shared__ alignas(16) __bf16 sp[128][136];  // softmax probs (A-layout staging)

    const int b    = blockIdx.x;
    const int wm   = b & 63;          // mask group = window % 64
    const int tid  = threadIdx.x;
    const int wave = tid >> 6;
    const int lane = tid & 63;
    const int quad = lane >> 4;
    const int l16  = lane & 15;
    const int mrow = wave * 32;

    const __bf16* wqkv_t  = (const __bf16*)(ws + WS_WQKV_T);
    const __bf16* wqkvm_t = (const __bf16*)(ws + WS_WQKVM_T);
    const float*  rpbg    = (const float*)(ws + WS_RPBG);

    // stage x window -> bf16 LDS (coalesced float4)
    {
        const float4* xg = (const float4*)(x + (size_t)b * 24576);
        #pragma unroll
        for (int i = 0; i < 24; ++i) {
            int f = tid + i * 256;            // 0..6143
            int row = f / 48;
            int c4 = (f - row * 48) * 4;
            float4 v = xg[f];
            xw[row][c4 + 0] = (__bf16)v.x;
            xw[row][c4 + 1] = (__bf16)v.y;
            xw[row][c4 + 2] = (__bf16)v.z;
            xw[row][c4 + 3] = (__bf16)v.w;
        }
    }
    __syncthreads();

    for (int branch = 0; branch < 2; ++branch) {
        const __bf16* wt = branch ? wqkvm_t : wqkv_t;
        if (branch) {
            // xw := bf16(xw + position_bias tiled along tokens)
            #pragma unroll
            for (int i = 0; i < 96; ++i) {
                int e = tid + i * 256;        // 0..24575
                int row = e / 192;
                int c = e - row * 192;
                xw[row][c] = (__bf16)((float)xw[row][c] +
                                      pos_bias[(row & 63) * 192 + c]);
            }
            __syncthreads();
        }

        for (int h = 0; h < 6; ++h) {
            // ---- QKV projection for this head: [128,192] @ [192,32] x3 ----
            #pragma unroll
            for (int sel = 0; sel < 3; ++sel) {
                const int colbase = sel * 192 + h * 32;
                f32x4 acc[2][2] = {};
                #pragma unroll
                for (int ks = 0; ks < 6; ++ks) {
                    const int k0 = ks * 32 + quad * 8;
                    bf16x8 a0 = *(const bf16x8*)&xw[mrow + l16][k0];
                    bf16x8 a1 = *(const bf16x8*)&xw[mrow + 16 + l16][k0];
                    #pragma unroll
                    for (int nt = 0; nt < 2; ++nt) {
                        bf16x8 bb = *(const bf16x8*)
                            &wt[(colbase + nt * 16 + l16) * 192 + k0];
                        acc[0][nt] = MFMA(a0, bb, acc[0][nt]);
                        acc[1][nt] = MFMA(a1, bb, acc[1][nt]);
                    }
                }
                #pragma unroll
                for (int mt = 0; mt < 2; ++mt)
                    #pragma unroll
                    for (int nt = 0; nt < 2; ++nt)
                        #pragma unroll
                        for (int r = 0; r < 4; ++r) {
                            int row = mrow + mt * 16 + quad * 4 + r;
                            int col = nt * 16 + l16;
                            __bf16 vv = (__bf16)acc[mt][nt][r];
                            if (sel == 0)      qh[row][col] = vv;
                            else if (sel == 1) kh[row][col] = vv;
                            else               vt[col][row] = vv;  // transposed
                        }
            }
            __syncthreads();

            if (branch == 0) {
                // ---- self: S = QK^T [32 rows x 128 keys] per wave ----
                f32x4 s[2][8];
                bf16x8 aq0 = *(const bf16x8*)&qh[mrow + l16][quad * 8];
                bf16x8 aq1 = *(const bf16x8*)&qh[mrow + 16 + l16][quad * 8];
                #pragma unroll
                for (int ct = 0; ct < 8; ++ct) {
                    bf16x8 bk = *(const bf16x8*)&kh[ct * 16 + l16][quad * 8];
                    f32x4 z = {};
                    s[0][ct] = MFMA(aq0, bk, z);
                    s[1][ct] = MFMA(aq1, bk, z);
                }
                float rl[2][4];
                #pragma unroll
                for (int mt = 0; mt < 2; ++mt) {
                    float mx[4] = {-3e38f, -3e38f, -3e38f, -3e38f};
                    #pragma unroll
                    for (int r = 0; r < 4; ++r) {
                        const int i = mrow + mt * 16 + quad * 4 + r;
                        const float* rb = rpbg + h * 16384 + i * 128;
                        const float* mk = mask + ((size_t)wm * 128 + i) * 128;
                        #pragma unroll
                        for (int ct = 0; ct < 8; ++ct) {
                            int j = ct * 16 + l16;
                            float sv = s[mt][ct][r] * SCALE_F + rb[j] + mk[j];
                            s[mt][ct][r] = sv;
                            mx[r] = fmaxf(mx[r], sv);
                        }
                    }
                    #pragma unroll
                    for (int r = 0; r < 4; ++r)
                        #pragma unroll
                        for (int off = 1; off < 16; off <<= 1)
                            mx[r] = fmaxf(mx[r], __shfl_xor(mx[r], off, 64));
                    float sum[4] = {0.f, 0.f, 0.f, 0.f};
                    #pragma unroll
                    for (int r = 0; r < 4; ++r)
                        #pragma unroll
                        for (int ct = 0; ct < 8; ++ct) {
                            float p = __expf(s[mt][ct][r] - mx[r]);
                            s[mt][ct][r] = p;
                            sum[r] += p;
                        }
                    #pragma unroll
                    for (int r = 0; r < 4; ++r) {
                        #pragma unroll
                        for (int off = 1; off < 16; off <<= 1)
                            sum[r] += __shfl_xor(sum[r], off, 64);
                        rl[mt][r] = 1.0f / sum[r];
                    }
                    #pragma unroll
                    for (int r = 0; r < 4; ++r) {
                        const int i = mrow + mt * 16 + quad * 4 + r;
                        #pragma unroll
                        for (int ct = 0; ct < 8; ++ct)
                            sp[i][ct * 16 + l16] = (__bf16)s[mt][ct][r];
                    }
                }
                // sp rows are wave-private; in-wave LDS RAW needs no barrier
                f32x4 o[2][2] = {};
                #pragma unroll
                for (int ks = 0; ks < 4; ++ks) {
                    const int k0 = ks * 32 + quad * 8;
                    bf16x8 p0 = *(const bf16x8*)&sp[mrow + l16][k0];
                    bf16x8 p1 = *(const bf16x8*)&sp[mrow + 16 + l16][k0];
                    #pragma unroll
                    for (int nt = 0; nt < 2; ++nt) {
                        bf16x8 bv = *(const bf16x8*)&vt[nt * 16 + l16][k0];
                        o[0][nt] = MFMA(p0, bv, o[0][nt]);
                        o[1][nt] = MFMA(p1, bv, o[1][nt]);
                    }
                }
                #pragma unroll
                for (int mt = 0; mt < 2; ++mt)
                    #pragma unroll
                    for (int nt = 0; nt < 2; ++nt)
                        #pragma unroll
                        for (int r = 0; r < 4; ++r) {
                            const int i = mrow + mt * 16 + quad * 4 + r;
                            const int c = 192 + h * 32 + nt * 16 + l16;
                            concat[((size_t)b * 128 + i) * 384 + c] =
                                (__bf16)(o[mt][nt][r] * rl[mt][r]);
                        }
            } else {
                // ---- mutual: queries 0..63 <-> keys 64..127 (and vice versa)
                const int kbase = (wave < 2) ? 64 : 0;
                f32x4 s[2][4];
                bf16x8 aq0 = *(const bf16x8*)&qh[mrow + l16][quad * 8];
                bf16x8 aq1 = *(const bf16x8*)&qh[mrow + 16 + l16][quad * 8];
                #pragma unroll
                for (int ct = 0; ct < 4; ++ct) {
                    bf16x8 bk = *(const bf16x8*)&kh[kbase + ct * 16 + l16][quad * 8];
                    f32x4 z = {};
                    s[0][ct] = MFMA(aq0, bk, z);
                    s[1][ct] = MFMA(aq1, bk, z);
                }
                float rl[2][4];
                #pragma unroll
                for (int mt = 0; mt < 2; ++mt) {
                    float mx[4] = {-3e38f, -3e38f, -3e38f, -3e38f};
                    #pragma unroll
                    for (int r = 0; r < 4; ++r) {
                        const int i = mrow + mt * 16 + quad * 4 + r;
                        const float* mk = mask + ((size_t)wm * 128 + (i & 63)) * 128;
                        #pragma unroll
                        for (int ct = 0; ct < 4; ++ct) {
                            float sv = s[mt][ct][r] * SCALE_F + mk[ct * 16 + l16];
                            s[mt][ct][r] = sv;
                            mx[r] = fmaxf(mx[r], sv);
                        }
                    }
                    #pragma unroll
                    for (int r = 0; r < 4; ++r)
                        #pragma unroll
                        for (int off = 1; off < 16; off <<= 1)
                            mx[r] = fmaxf(mx[r], __shfl_xor(mx[r], off, 64));
                    float sum[4] = {0.f, 0.f, 0.f, 0.f};
                    #pragma unroll
                    for (int r = 0; r < 4; ++r)
                        #pragma unroll
                        for (int ct = 0; ct < 4; ++ct) {
                            float p = __expf(s[mt][ct][r] - mx[r]);
                            s[mt][ct][r] = p;
                            sum[r] += p;
                        }
                    #pragma unroll
                    for (int r = 0; r < 4; ++r) {
                        #pragma unroll
                        for (int off = 1; off < 16; off <<= 1)
                            sum[r] += __shfl_xor(sum[r], off, 64);
                        rl[mt][r] = 1.0f / sum[r];
                    }
                    #pragma unroll
                    for (int r = 0; r < 4; ++r) {
                        const int i = mrow + mt * 16 + quad * 4 + r;
                        #pragma unroll
                        for (int ct = 0; ct < 4; ++ct)
                            sp[i][ct * 16 + l16] = (__bf16)s[mt][ct][r];
                    }
                }
                f32x4 o[2][2] = {};
                #pragma unroll
                for (int ks = 0; ks < 2; ++ks) {
                    const int k0 = ks * 32 + quad * 8;
                    bf16x8 p0 = *(const bf16x8*)&sp[mrow + l16][k0];
                    bf16x8 p1 = *(const bf16x8*)&sp[mrow + 16 + l16][k0];
                    #pragma unroll
                    for (int nt = 0; nt < 2; ++nt) {
                        bf16x8 bv = *(const bf16x8*)&vt[nt * 16 + l16][kbase + k0];
                        o[0][nt] = MFMA(p0, bv, o[0][nt]);
                        o[1][nt] = MFMA(p1, bv, o[1][nt]);
                    }
                }
                #pragma unroll
                for (int mt = 0; mt < 2; ++mt)
                    #pragma unroll
                    for (int nt = 0; nt < 2; ++nt)
                        #pragma unroll
                        for (int r = 0; r < 4; ++r) {
                            const int i = mrow + mt * 16 + quad * 4 + r;
                            const int ot = (i + 64) & 127;   // output token rotation
                            concat[((size_t)b * 128 + ot) * 384 + h * 32 + nt * 16 + l16] =
                                (__bf16)(o[mt][nt][r] * rl[mt][r]);
                        }
            }
            __syncthreads();   // qh/kh/vt reused next head (cross-wave readers)
        }
    }
}

// ---------------------------------------------------------------------------
// out[t, :] = concat[t, :384] @ w_proj + b_proj.  concat aliases d_out:
// each block stages its 64 rows to LDS, barriers, then overwrites the same
// bytes with fp32 — row ranges are block-disjoint, so this is race-free.
__global__ __launch_bounds__(256, 1)
void proj_kernel(const __bf16* __restrict__ concat,
                 const char* __restrict__ ws,
                 const float* __restrict__ b_proj,
                 float* __restrict__ out) {
    __shared__ alignas(16) __bf16 at[64][392];
    const __bf16* wproj_t = (const __bf16*)(ws + WS_WPROJ_T);
    const int tid  = threadIdx.x;
    const int wave = tid >> 6;
    const int lane = tid & 63;
    const int quad = lane >> 4;
    const int l16  = lane & 15;
    const size_t r0 = (size_t)blockIdx.x * 64;

    const uint4* cg = (const uint4*)(concat + r0 * 384);
    #pragma unroll
    for (int i = 0; i < 12; ++i) {
        int f = tid + i * 256;                // 0..3071
        int row = f / 48;
        int c8 = (f - row * 48) * 8;
        *(uint4*)&at[row][c8] = cg[f];
    }
    __syncthreads();

    const int m0 = wave * 16;
    f32x4 acc[12] = {};
    #pragma unroll
    for (int ks = 0; ks < 12; ++ks) {
        const int k0 = ks * 32 + quad * 8;
        bf16x8 a = *(const bf16x8*)&at[m0 + l16][k0];
        #pragma unroll
        for (int nt = 0; nt < 12; ++nt) {
            bf16x8 bb = *(const bf16x8*)&wproj_t[(nt * 16 + l16) * 384 + k0];
            acc[nt] = MFMA(a, bb, acc[nt]);
        }
    }
    #pragma unroll
    for (int nt = 0; nt < 12; ++nt) {
        const int c = nt * 16 + l16;
        const float bias = b_proj[c];
        #pragma unroll
        for (int r = 0; r < 4; ++r) {
            int row = m0 + quad * 4 + r;
            out[(r0 + row) * 192 + c] = acc[nt][r] + bias;
        }
    }
}

// ---------------------------------------------------------------------------
extern "C" void kernel_launch(void* const* d_in, const int* in_sizes, int n_in,
                              void* d_out, int out_size, void* d_ws, size_t ws_size,
                              hipStream_t stream) {
    const float* x       = (const float*)d_in[0];
    const float* mask    = (const float*)d_in[1];
    const float* w_qkv   = (const float*)d_in[2];
    const float* w_qkvm  = (const float*)d_in[3];
    const float* w_proj  = (const float*)d_in[4];
    const float* b_proj  = (const float*)d_in[5];
    const float* rpb     = (const float*)d_in[6];
    const float* pos_b   = (const float*)d_in[7];
    const int*   rel_idx = (const int*)d_in[8];

    if (ws_size < WS_NEEDED) return;  // fail loudly (wrong output) vs corrupt

    char*   ws     = (char*)d_ws;
    __bf16* concat = (__bf16*)d_out;   // 131072*384 bf16 == out_size*4 bytes, exact
    float*  out    = (float*)d_out;

    prep_kernel<<<1104, 256, 0, stream>>>(w_qkv, w_qkvm, w_proj, rpb, rel_idx, ws);
    attn_kernel<<<1024, 256, 0, stream>>>(x, mask, pos_b, ws, concat);
    proj_kernel<<<2048, 256, 0, stream>>>(concat, ws, b_proj, out);
}

// Round 2
// 1016.152 us; speedup vs baseline: 1.1358x; 1.1358x over previous
//
#include <hip/hip_runtime.h>
#include <hip/hip_bf16.h>
#include <math.h>

// ---------------------------------------------------------------------------
// WindowAttention (self + mutual), MI355X / gfx950.
// R1: occupancy restructure. One block per (window, branch), 8 waves x 16
// query rows, LDS 77056 B -> 2 blocks/CU, VGPR capped at 128 (4 waves/SIMD).
// ---------------------------------------------------------------------------

#define SCALE_F 0.17677669529663687f  // 32^-0.5 (folded into Q weight cols)

// ws layout (bytes)
#define WS_WQKV_T   0u        // [576][192] bf16 (W^T: [col][k]; q-cols pre-scaled)
#define WS_WQKVM_T  221184u   // [576][192] bf16
#define WS_WPROJ_T  442368u   // [384][192]->[n][k] bf16
#define WS_RPBG     589824u   // [6][128][128] f32
#define WS_NEEDED   983040u

typedef __bf16 bf16x8 __attribute__((ext_vector_type(8)));
typedef float  f32x4  __attribute__((ext_vector_type(4)));

#define MFMA(a, b, c) __builtin_amdgcn_mfma_f32_16x16x32_bf16((a), (b), (c), 0, 0, 0)

// ---------------------------------------------------------------------------
__global__ void prep_kernel(const float* __restrict__ w_qkv,
                            const float* __restrict__ w_qkvm,
                            const float* __restrict__ w_proj,
                            const float* __restrict__ rpb_table,
                            const int*   __restrict__ rel_idx,
                            char* __restrict__ ws) {
    int idx = blockIdx.x * 256 + threadIdx.x;
    if (idx < 110592) {                       // wqkv_t / wqkvm_t: [col][k]
        int col = idx / 192, k = idx - col * 192;
        float sc = (col < 192) ? SCALE_F : 1.0f;   // pre-scale Q columns
        ((__bf16*)(ws + WS_WQKV_T))[idx]  = (__bf16)(w_qkv[k * 576 + col] * sc);
        ((__bf16*)(ws + WS_WQKVM_T))[idx] = (__bf16)(w_qkvm[k * 576 + col] * sc);
    } else if (idx < 184320) {                // wproj_t: [n][k]
        int o = idx - 110592;
        int n = o / 384, k = o - n * 384;
        ((__bf16*)(ws + WS_WPROJ_T))[o] = (__bf16)w_proj[k * 192 + n];
    } else if (idx < 282624) {                // rpbg[h][i][j]
        int o = idx - 184320;
        int h = o / 16384, r = o - h * 16384;
        ((float*)(ws + WS_RPBG))[o] = rpb_table[rel_idx[r] * 6 + h];
    }
}

// ---------------------------------------------------------------------------
// Block = (window, branch). 512 threads = 8 waves; wave w owns query rows
// [16w, 16w+16). MFMA 16x16x32 bf16 layouts (HW-verified):
//   A[m = lane&15][k = quad*8 + j]
//   B[k = quad*8 + j][n = lane&15]
//   D: col = lane&15, row = quad*4 + reg
// LDS map (77056 B total, 2 blocks/CU):
//   xw [128][196] @ 0       (50176 B)   x (or x+pb) bf16, lives whole kernel
//   qh [128][36]  @ 50176   ( 9216 B)   Q head (pre-scaled), wave-private rows
//   kh [128][36]  @ 59392   ( 9216 B)   K head
//   vt [ 32][132] @ 68608   ( 8448 B)   V head transposed [dim][token]
//   sp [128][68]  @ 50176   (17408 B)   P staging, OVERLAYS qh+kh (guarded by
//                                       the post-softmax barrier)
__global__ __launch_bounds__(512, 4)
void attn_kernel(const float* __restrict__ x,
                 const float* __restrict__ mask,
                 const float* __restrict__ pos_bias,
                 const char*  __restrict__ ws,
                 __bf16* __restrict__ concat) {
    __shared__ alignas(16) char smem[77056];
    __bf16 (*xw)[196] = (__bf16(*)[196])(smem);
    __bf16 (*qh)[36]  = (__bf16(*)[36])(smem + 50176);
    __bf16 (*kh)[36]  = (__bf16(*)[36])(smem + 59392);
    __bf16 (*vt)[132] = (__bf16(*)[132])(smem + 68608);
    __bf16 (*sp)[68]  = (__bf16(*)[68])(smem + 50176);

    const int b      = blockIdx.x >> 1;
    const int branch = blockIdx.x & 1;
    const int wm     = b & 63;
    const int tid    = threadIdx.x;
    const int lane   = tid & 63;
    const int quad   = lane >> 4;
    const int l16    = lane & 15;
    const int mrow   = (tid >> 6) * 16;

    const __bf16* wt   = (const __bf16*)(ws + (branch ? WS_WQKVM_T : WS_WQKV_T));
    const float*  rpbg = (const float*)(ws + WS_RPBG);

    // stage x window (+ position bias for mutual branch) -> bf16 LDS
    {
        const float4* xg = (const float4*)(x + (size_t)b * 24576);
        const float4* pg = (const float4*)pos_bias;
        #pragma unroll
        for (int i = 0; i < 12; ++i) {
            int f = tid + i * 512;            // 0..6143
            int row = f / 48;
            int cc = f - row * 48;
            float4 v = xg[f];
            if (branch) {
                float4 p = pg[(row & 63) * 48 + cc];
                v.x += p.x; v.y += p.y; v.z += p.z; v.w += p.w;
            }
            int c4 = cc * 4;
            xw[row][c4 + 0] = (__bf16)v.x;
            xw[row][c4 + 1] = (__bf16)v.y;
            xw[row][c4 + 2] = (__bf16)v.z;
            xw[row][c4 + 3] = (__bf16)v.w;
        }
    }
    __syncthreads();

    for (int h = 0; h < 6; ++h) {
        // ---- QKV projection for head h: each wave does a 16-row M-tile ----
        #pragma unroll
        for (int sel = 0; sel < 3; ++sel) {
            const int colbase = sel * 192 + h * 32;
            f32x4 acc[2] = {};
            #pragma unroll
            for (int ks = 0; ks < 6; ++ks) {
                const int k0 = ks * 32 + quad * 8;
                bf16x8 a = *(const bf16x8*)&xw[mrow + l16][k0];
                #pragma unroll
                for (int nt = 0; nt < 2; ++nt) {
                    bf16x8 bb = *(const bf16x8*)
                        &wt[(colbase + nt * 16 + l16) * 192 + k0];
                    acc[nt] = MFMA(a, bb, acc[nt]);
                }
            }
            #pragma unroll
            for (int nt = 0; nt < 2; ++nt)
                #pragma unroll
                for (int r = 0; r < 4; ++r) {
                    int row = mrow + quad * 4 + r;
                    int col = nt * 16 + l16;
                    __bf16 vv = (__bf16)acc[nt][r];
                    if (sel == 0)      qh[row][col] = vv;
                    else if (sel == 1) kh[row][col] = vv;
                    else               vt[col][row] = vv;   // transposed
                }
        }
        __syncthreads();   // qh/kh/vt visible to all waves

        if (branch == 0) {
            // ---- self: S = QK^T [16 rows x 128 keys] per wave ----
            bf16x8 aq = *(const bf16x8*)&qh[mrow + l16][quad * 8];
            f32x4 s[8];
            #pragma unroll
            for (int ct = 0; ct < 8; ++ct) {
                bf16x8 bk = *(const bf16x8*)&kh[ct * 16 + l16][quad * 8];
                f32x4 z = {};
                s[ct] = MFMA(aq, bk, z);
            }
            float rl[4];
            #pragma unroll
            for (int r = 0; r < 4; ++r) {
                const int i = mrow + quad * 4 + r;
                const float* rb = rpbg + h * 16384 + i * 128;
                const float* mk = mask + ((size_t)wm * 128 + i) * 128;
                float mx = -3e38f;
                #pragma unroll
                for (int ct = 0; ct < 8; ++ct) {
                    int j = ct * 16 + l16;
                    float sv = s[ct][r] + rb[j] + mk[j];
                    s[ct][r] = sv;
                    mx = fmaxf(mx, sv);
                }
                #pragma unroll
                for (int off = 1; off < 16; off <<= 1)
                    mx = fmaxf(mx, __shfl_xor(mx, off, 64));
                float sum = 0.f;
                #pragma unroll
                for (int ct = 0; ct < 8; ++ct) {
                    float p = __expf(s[ct][r] - mx);
                    s[ct][r] = p;
                    sum += p;
                }
                #pragma unroll
                for (int off = 1; off < 16; off <<= 1)
                    sum += __shfl_xor(sum, off, 64);
                rl[r] = 1.0f / sum;
            }
            __syncthreads();   // all waves done reading qh/kh -> sp may overlay

            // ---- PV in two key-halves through the small sp buffer ----
            f32x4 o[2] = {};
            #pragma unroll
            for (int kh2 = 0; kh2 < 2; ++kh2) {
                #pragma unroll
                for (int r = 0; r < 4; ++r) {
                    const int i = mrow + quad * 4 + r;
                    #pragma unroll
                    for (int ct = 0; ct < 4; ++ct)
                        sp[i][ct * 16 + l16] = (__bf16)s[kh2 * 4 + ct][r];
                }
                #pragma unroll
                for (int ks2 = 0; ks2 < 2; ++ks2) {
                    const int k0 = ks2 * 32 + quad * 8;
                    bf16x8 p = *(const bf16x8*)&sp[mrow + l16][k0];
                    #pragma unroll
                    for (int nt = 0; nt < 2; ++nt) {
                        bf16x8 bv = *(const bf16x8*)&vt[nt * 16 + l16][kh2 * 64 + k0];
                        o[nt] = MFMA(p, bv, o[nt]);
                    }
                }
            }
            #pragma unroll
            for (int nt = 0; nt < 2; ++nt)
                #pragma unroll
                for (int r = 0; r < 4; ++r) {
                    const int i = mrow + quad * 4 + r;
                    concat[((size_t)b * 128 + i) * 384 + 192 + h * 32 + nt * 16 + l16] =
                        (__bf16)(o[nt][r] * rl[r]);
                }
        } else {
            // ---- mutual: queries in one half attend keys of the other ----
            const int kbase = (mrow < 64) ? 64 : 0;
            bf16x8 aq = *(const bf16x8*)&qh[mrow + l16][quad * 8];
            f32x4 s[4];
            #pragma unroll
            for (int ct = 0; ct < 4; ++ct) {
                bf16x8 bk = *(const bf16x8*)&kh[kbase + ct * 16 + l16][quad * 8];
                f32x4 z = {};
                s[ct] = MFMA(aq, bk, z);
            }
            float rl[4];
            #pragma unroll
            for (int r = 0; r < 4; ++r) {
                const int i = mrow + quad * 4 + r;
                const float* mk = mask + ((size_t)wm * 128 + (i & 63)) * 128;
                float mx = -3e38f;
                #pragma unroll
                for (int ct = 0; ct < 4; ++ct) {
                    float sv = s[ct][r] + mk[ct * 16 + l16];
                    s[ct][r] = sv;
                    mx = fmaxf(mx, sv);
                }
                #pragma unroll
                for (int off = 1; off < 16; off <<= 1)
                    mx = fmaxf(mx, __shfl_xor(mx, off, 64));
                float sum = 0.f;
                #pragma unroll
                for (int ct = 0; ct < 4; ++ct) {
                    float p = __expf(s[ct][r] - mx);
                    s[ct][r] = p;
                    sum += p;
                }
                #pragma unroll
                for (int off = 1; off < 16; off <<= 1)
                    sum += __shfl_xor(sum, off, 64);
                rl[r] = 1.0f / sum;
            }
            __syncthreads();   // qh/kh reads done -> sp overlay safe

            #pragma unroll
            for (int r = 0; r < 4; ++r) {
                const int i = mrow + quad * 4 + r;
                #pragma unroll
                for (int ct = 0; ct < 4; ++ct)
                    sp[i][ct * 16 + l16] = (__bf16)s[ct][r];
            }
            f32x4 o[2] = {};
            #pragma unroll
            for (int ks2 = 0; ks2 < 2; ++ks2) {
                const int k0 = ks2 * 32 + quad * 8;
                bf16x8 p = *(const bf16x8*)&sp[mrow + l16][k0];
                #pragma unroll
                for (int nt = 0; nt < 2; ++nt) {
                    bf16x8 bv = *(const bf16x8*)&vt[nt * 16 + l16][kbase + k0];
                    o[nt] = MFMA(p, bv, o[nt]);
                }
            }
            #pragma unroll
            for (int nt = 0; nt < 2; ++nt)
                #pragma unroll
                for (int r = 0; r < 4; ++r) {
                    const int i = mrow + quad * 4 + r;
                    const int ot = (i + 64) & 127;   // output token rotation
                    concat[((size_t)b * 128 + ot) * 384 + h * 32 + nt * 16 + l16] =
                        (__bf16)(o[nt][r] * rl[r]);
                }
        }
        __syncthreads();   // sp/vt readers done before next head's QKV writes
    }
}

// ---------------------------------------------------------------------------
// out[t, :] = concat[t, :384] @ w_proj + b_proj.  concat aliases d_out:
// stage 64 rows to LDS, barrier, overwrite same bytes with fp32.
__global__ __launch_bounds__(256, 3)
void proj_kernel(const __bf16* __restrict__ concat,
                 const char* __restrict__ ws,
                 const float* __restrict__ b_proj,
                 float* __restrict__ out) {
    __shared__ alignas(16) __bf16 at[64][392];
    const __bf16* wproj_t = (const __bf16*)(ws + WS_WPROJ_T);
    const int tid  = threadIdx.x;
    const int wave = tid >> 6;
    const int lane = tid & 63;
    const int quad = lane >> 4;
    const int l16  = lane & 15;
    const size_t r0 = (size_t)blockIdx.x * 64;

    const uint4* cg = (const uint4*)(concat + r0 * 384);
    #pragma unroll
    for (int i = 0; i < 12; ++i) {
        int f = tid + i * 256;                // 0..3071
        int row = f / 48;
        int c8 = (f - row * 48) * 8;
        *(uint4*)&at[row][c8] = cg[f];
    }
    __syncthreads();

    const int m0 = wave * 16;
    f32x4 acc[12] = {};
    #pragma unroll
    for (int ks = 0; ks < 12; ++ks) {
        const int k0 = ks * 32 + quad * 8;
        bf16x8 a = *(const bf16x8*)&at[m0 + l16][k0];
        #pragma unroll
        for (int nt = 0; nt < 12; ++nt) {
            bf16x8 bb = *(const bf16x8*)&wproj_t[(nt * 16 + l16) * 384 + k0];
            acc[nt] = MFMA(a, bb, acc[nt]);
        }
    }
    #pragma unroll
    for (int nt = 0; nt < 12; ++nt) {
        const int c = nt * 16 + l16;
        const float bias = b_proj[c];
        #pragma unroll
        for (int r = 0; r < 4; ++r) {
            int row = m0 + quad * 4 + r;
            out[(r0 + row) * 192 + c] = acc[nt][r] + bias;
        }
    }
}

// ---------------------------------------------------------------------------
extern "C" void kernel_launch(void* const* d_in, const int* in_sizes, int n_in,
                              void* d_out, int out_size, void* d_ws, size_t ws_size,
                              hipStream_t stream) {
    const float* x       = (const float*)d_in[0];
    const float* mask    = (const float*)d_in[1];
    const float* w_qkv   = (const float*)d_in[2];
    const float* w_qkvm  = (const float*)d_in[3];
    const float* w_proj  = (const float*)d_in[4];
    const float* b_proj  = (const float*)d_in[5];
    const float* rpb     = (const float*)d_in[6];
    const float* pos_b   = (const float*)d_in[7];
    const int*   rel_idx = (const int*)d_in[8];

    if (ws_size < WS_NEEDED) return;

    char*   ws     = (char*)d_ws;
    __bf16* concat = (__bf16*)d_out;   // 131072*384 bf16 == out bytes, exact fit
    float*  out    = (float*)d_out;

    prep_kernel<<<1104, 256, 0, stream>>>(w_qkv, w_qkvm, w_proj, rpb, rel_idx, ws);
    attn_kernel<<<2048, 512, 0, stream>>>(x, mask, pos_b, ws, concat);
    proj_kernel<<<2048, 256, 0, stream>>>(concat, ws, b_proj, out);
}

// Round 3
// 758.007 us; speedup vs baseline: 1.5226x; 1.3406x over previous
//
#include <hip/hip_runtime.h>
#include <hip/hip_bf16.h>
#include <math.h>

// ---------------------------------------------------------------------------
// WindowAttention (self + mutual), MI355X / gfx950.
// R2: barrier-minimized. Block = (window, branch), 512 thr, 4 barriers/block.
// x lives in registers as A-fragments; QKV per 3-head group; attention runs
// barrier-free (wave-private P staging). proj stages weights in LDS by K-half.
// ---------------------------------------------------------------------------

#define SCALE_F 0.17677669529663687f  // 32^-0.5 (folded into Q weight cols)

// ws layout (bytes)
#define WS_WQKV_T   0u        // [576][192] bf16 (W^T: [col][k]; q-cols pre-scaled)
#define WS_WQKVM_T  221184u   // [576][192] bf16
#define WS_WPROJ_T  442368u   // [192 n][384 k] bf16
#define WS_RPBG     589824u   // [6][128][128] bf16 (bias gather resolved)
#define WS_NEEDED   983040u

typedef __bf16 bf16x8 __attribute__((ext_vector_type(8)));
typedef float  f32x4  __attribute__((ext_vector_type(4)));

#define MFMA(a, b, c) __builtin_amdgcn_mfma_f32_16x16x32_bf16((a), (b), (c), 0, 0, 0)

// ---------------------------------------------------------------------------
__global__ void prep_kernel(const float* __restrict__ w_qkv,
                            const float* __restrict__ w_qkvm,
                            const float* __restrict__ w_proj,
                            const float* __restrict__ rpb_table,
                            const int*   __restrict__ rel_idx,
                            char* __restrict__ ws) {
    int idx = blockIdx.x * 256 + threadIdx.x;
    if (idx < 110592) {                       // wqkv_t / wqkvm_t: [col][k]
        int col = idx / 192, k = idx - col * 192;
        float sc = (col < 192) ? SCALE_F : 1.0f;   // pre-scale Q columns
        ((__bf16*)(ws + WS_WQKV_T))[idx]  = (__bf16)(w_qkv[k * 576 + col] * sc);
        ((__bf16*)(ws + WS_WQKVM_T))[idx] = (__bf16)(w_qkvm[k * 576 + col] * sc);
    } else if (idx < 184320) {                // wproj_t: [n][k]
        int o = idx - 110592;
        int n = o / 384, k = o - n * 384;
        ((__bf16*)(ws + WS_WPROJ_T))[o] = (__bf16)w_proj[k * 192 + n];
    } else if (idx < 282624) {                // rpbg[h][i][j] -> bf16
        int o = idx - 184320;
        int h = o / 16384, r = o - h * 16384;
        ((__bf16*)(ws + WS_RPBG))[o] = (__bf16)rpb_table[rel_idx[r] * 6 + h];
    }
}

// ---------------------------------------------------------------------------
// Block = (window, branch). 512 threads = 8 waves; wave w owns query rows
// [16w, 16w+16). MFMA 16x16x32 bf16 layouts (HW-verified):
//   A[m = lane&15][k = quad*8 + j]
//   B[k = quad*8 + j][n = lane&15]
//   D: col = lane&15, row = quad*4 + reg
// LDS (79,360 B -> 2 blocks/CU):
//   kh3 [128][104]  K for 3 heads (cols = local 96 + pad; stride 208 B)
//   vt3 [ 96][136]  V^T for 3 heads [dim][token]
//   qs  [8][16][104] wave-private: Q staging, then P staging (no barriers)
__global__ __launch_bounds__(512, 4)
void attn_kernel(const float* __restrict__ x,
                 const float* __restrict__ mask,
                 const float* __restrict__ pos_bias,
                 const char*  __restrict__ ws,
                 __bf16* __restrict__ concat) {
    __shared__ alignas(16) __bf16 kh3[128][104];
    __shared__ alignas(16) __bf16 vt3[96][136];
    __shared__ alignas(16) __bf16 qs[8][16][104];

    const int b      = blockIdx.x >> 1;
    const int branch = blockIdx.x & 1;
    const int wm     = b & 63;
    const int tid    = threadIdx.x;
    const int wave   = tid >> 6;
    const int lane   = tid & 63;
    const int quad   = lane >> 4;
    const int l16    = lane & 15;
    const int mrow   = wave * 16;

    const __bf16* wt   = (const __bf16*)(ws + (branch ? WS_WQKVM_T : WS_WQKV_T));
    const __bf16* rpbg = (const __bf16*)(ws + WS_RPBG);

    // ---- x rows for this wave -> A-fragments in registers (reused 6x) ----
    bf16x8 afrag[6];
    {
        const float* xr = x + (size_t)b * 24576 + (mrow + l16) * 192;
        const float* pr = pos_bias + ((mrow + l16) & 63) * 192;
        #pragma unroll
        for (int ks = 0; ks < 6; ++ks) {
            const int k0 = ks * 32 + quad * 8;
            float4 v0 = *(const float4*)(xr + k0);
            float4 v1 = *(const float4*)(xr + k0 + 4);
            if (branch) {
                float4 p0 = *(const float4*)(pr + k0);
                float4 p1 = *(const float4*)(pr + k0 + 4);
                v0.x += p0.x; v0.y += p0.y; v0.z += p0.z; v0.w += p0.w;
                v1.x += p1.x; v1.y += p1.y; v1.z += p1.z; v1.w += p1.w;
            }
            bf16x8 f;
            f[0] = (__bf16)v0.x; f[1] = (__bf16)v0.y;
            f[2] = (__bf16)v0.z; f[3] = (__bf16)v0.w;
            f[4] = (__bf16)v1.x; f[5] = (__bf16)v1.y;
            f[6] = (__bf16)v1.z; f[7] = (__bf16)v1.w;
            afrag[ks] = f;
        }
    }

    for (int g = 0; g < 2; ++g) {
        const int hc = g * 96;          // weight col offset of this head group

        // ---- K (3 heads) -> kh3 ----
        {
            f32x4 acc[6] = {};
            #pragma unroll
            for (int ks = 0; ks < 6; ++ks) {
                const int k0 = ks * 32 + quad * 8;
                #pragma unroll
                for (int nt = 0; nt < 6; ++nt) {
                    bf16x8 bb = *(const bf16x8*)&wt[(192 + hc + nt * 16 + l16) * 192 + k0];
                    acc[nt] = MFMA(afrag[ks], bb, acc[nt]);
                }
            }
            #pragma unroll
            for (int nt = 0; nt < 6; ++nt)
                #pragma unroll
                for (int r = 0; r < 4; ++r)
                    kh3[mrow + quad * 4 + r][nt * 16 + l16] = (__bf16)acc[nt][r];
        }
        // ---- V (3 heads) -> vt3 transposed [dim][token] ----
        {
            f32x4 acc[6] = {};
            #pragma unroll
            for (int ks = 0; ks < 6; ++ks) {
                const int k0 = ks * 32 + quad * 8;
                #pragma unroll
                for (int nt = 0; nt < 6; ++nt) {
                    bf16x8 bb = *(const bf16x8*)&wt[(384 + hc + nt * 16 + l16) * 192 + k0];
                    acc[nt] = MFMA(afrag[ks], bb, acc[nt]);
                }
            }
            #pragma unroll
            for (int nt = 0; nt < 6; ++nt)
                #pragma unroll
                for (int r = 0; r < 4; ++r)
                    vt3[nt * 16 + l16][mrow + quad * 4 + r] = (__bf16)acc[nt][r];
        }
        // ---- Q (3 heads, pre-scaled) -> wave-private qs -> registers ----
        bf16x8 aq[3];
        {
            f32x4 acc[6] = {};
            #pragma unroll
            for (int ks = 0; ks < 6; ++ks) {
                const int k0 = ks * 32 + quad * 8;
                #pragma unroll
                for (int nt = 0; nt < 6; ++nt) {
                    bf16x8 bb = *(const bf16x8*)&wt[(hc + nt * 16 + l16) * 192 + k0];
                    acc[nt] = MFMA(afrag[ks], bb, acc[nt]);
                }
            }
            #pragma unroll
            for (int nt = 0; nt < 6; ++nt)
                #pragma unroll
                for (int r = 0; r < 4; ++r)
                    qs[wave][quad * 4 + r][nt * 16 + l16] = (__bf16)acc[nt][r];
            #pragma unroll
            for (int hl = 0; hl < 3; ++hl)
                aq[hl] = *(const bf16x8*)&qs[wave][l16][hl * 32 + quad * 8];
        }
        __syncthreads();    // K/V visible; Q already private in regs

        __bf16 (*spw)[104] = qs[wave];   // Q slot is dead -> P staging

        // ================= barrier-free attention, 3 heads =================
        if (branch == 0) {
            for (int hl = 0; hl < 3; ++hl) {
                const int h = g * 3 + hl;
                f32x4 s[8];
                #pragma unroll
                for (int ct = 0; ct < 8; ++ct) {
                    bf16x8 bk = *(const bf16x8*)&kh3[ct * 16 + l16][hl * 32 + quad * 8];
                    f32x4 z = {};
                    s[ct] = MFMA(aq[hl], bk, z);
                }
                float rl[4];
                #pragma unroll
                for (int r = 0; r < 4; ++r) {
                    const int i = mrow + quad * 4 + r;
                    const __bf16* rb = rpbg + h * 16384 + i * 128 + l16;
                    const float*  mk = mask + ((size_t)wm * 128 + i) * 128 + l16;
                    float bias[8];
                    #pragma unroll
                    for (int ct = 0; ct < 8; ++ct)
                        bias[ct] = (float)rb[ct * 16] + mk[ct * 16];
                    float mx = -3e38f;
                    #pragma unroll
                    for (int ct = 0; ct < 8; ++ct) {
                        float sv = s[ct][r] + bias[ct];
                        s[ct][r] = sv;
                        mx = fmaxf(mx, sv);
                    }
                    #pragma unroll
                    for (int off = 1; off < 16; off <<= 1)
                        mx = fmaxf(mx, __shfl_xor(mx, off, 64));
                    float sum = 0.f;
                    #pragma unroll
                    for (int ct = 0; ct < 8; ++ct) {
                        float p = __expf(s[ct][r] - mx);
                        s[ct][r] = p;
                        sum += p;
                    }
                    #pragma unroll
                    for (int off = 1; off < 16; off <<= 1)
                        sum += __shfl_xor(sum, off, 64);
                    rl[r] = 1.0f / sum;
                }
                // P -> A-layout via wave-private staging, 32-key chunks
                f32x4 o[2] = {};
                #pragma unroll
                for (int kc = 0; kc < 4; ++kc) {
                    #pragma unroll
                    for (int r = 0; r < 4; ++r) {
                        const int il = quad * 4 + r;
                        spw[il][l16]      = (__bf16)s[kc * 2][r];
                        spw[il][16 + l16] = (__bf16)s[kc * 2 + 1][r];
                    }
                    bf16x8 p = *(const bf16x8*)&spw[l16][quad * 8];
                    #pragma unroll
                    for (int nt = 0; nt < 2; ++nt) {
                        bf16x8 bv = *(const bf16x8*)&vt3[hl * 32 + nt * 16 + l16][kc * 32 + quad * 8];
                        o[nt] = MFMA(p, bv, o[nt]);
                    }
                }
                #pragma unroll
                for (int nt = 0; nt < 2; ++nt)
                    #pragma unroll
                    for (int r = 0; r < 4; ++r) {
                        const int i = mrow + quad * 4 + r;
                        concat[((size_t)b * 128 + i) * 384 + 192 + h * 32 + nt * 16 + l16] =
                            (__bf16)(o[nt][r] * rl[r]);
                    }
            }
        } else {
            const int kbase = (mrow < 64) ? 64 : 0;
            for (int hl = 0; hl < 3; ++hl) {
                const int h = g * 3 + hl;
                f32x4 s[4];
                #pragma unroll
                for (int ct = 0; ct < 4; ++ct) {
                    bf16x8 bk = *(const bf16x8*)&kh3[kbase + ct * 16 + l16][hl * 32 + quad * 8];
                    f32x4 z = {};
                    s[ct] = MFMA(aq[hl], bk, z);
                }
                float rl[4];
                #pragma unroll
                for (int r = 0; r < 4; ++r) {
                    const int i = mrow + quad * 4 + r;
                    const float* mk = mask + ((size_t)wm * 128 + (i & 63)) * 128 + l16;
                    float bias[4];
                    #pragma unroll
                    for (int ct = 0; ct < 4; ++ct)
                        bias[ct] = mk[ct * 16];
                    float mx = -3e38f;
                    #pragma unroll
                    for (int ct = 0; ct < 4; ++ct) {
                        float sv = s[ct][r] + bias[ct];
                        s[ct][r] = sv;
                        mx = fmaxf(mx, sv);
                    }
                    #pragma unroll
                    for (int off = 1; off < 16; off <<= 1)
                        mx = fmaxf(mx, __shfl_xor(mx, off, 64));
                    float sum = 0.f;
                    #pragma unroll
                    for (int ct = 0; ct < 4; ++ct) {
                        float p = __expf(s[ct][r] - mx);
                        s[ct][r] = p;
                        sum += p;
                    }
                    #pragma unroll
                    for (int off = 1; off < 16; off <<= 1)
                        sum += __shfl_xor(sum, off, 64);
                    rl[r] = 1.0f / sum;
                }
                f32x4 o[2] = {};
                #pragma unroll
                for (int kc = 0; kc < 2; ++kc) {
                    #pragma unroll
                    for (int r = 0; r < 4; ++r) {
                        const int il = quad * 4 + r;
                        spw[il][l16]      = (__bf16)s[kc * 2][r];
                        spw[il][16 + l16] = (__bf16)s[kc * 2 + 1][r];
                    }
                    bf16x8 p = *(const bf16x8*)&spw[l16][quad * 8];
                    #pragma unroll
                    for (int nt = 0; nt < 2; ++nt) {
                        bf16x8 bv = *(const bf16x8*)&vt3[hl * 32 + nt * 16 + l16][kbase + kc * 32 + quad * 8];
                        o[nt] = MFMA(p, bv, o[nt]);
                    }
                }
                #pragma unroll
                for (int nt = 0; nt < 2; ++nt)
                    #pragma unroll
                    for (int r = 0; r < 4; ++r) {
                        const int i = mrow + quad * 4 + r;
                        const int ot = (i + 64) & 127;   // output token rotation
                        concat[((size_t)b * 128 + ot) * 384 + h * 32 + nt * 16 + l16] =
                            (__bf16)(o[nt][r] * rl[r]);
                    }
            }
        }
        __syncthreads();    // kh3/vt3 readers done before next group's writes
    }
}

// ---------------------------------------------------------------------------
// out = concat @ w_proj + b_proj, 128 rows/block, weights LDS-staged in two
// K-halves (76.8 KB -> 2 blocks/CU). concat aliases d_out: all A-reads finish
// before any store (stores only in the epilogue), rows are block-disjoint.
__global__ __launch_bounds__(512, 4)
void proj_kernel(const __bf16* __restrict__ concat,
                 const char* __restrict__ ws,
                 const float* __restrict__ b_proj,
                 float* __restrict__ out) {
    __shared__ alignas(16) __bf16 bwh[192][200];   // [n][k-half]
    const __bf16* wproj_t = (const __bf16*)(ws + WS_WPROJ_T);
    const int tid  = threadIdx.x;
    const int wave = tid >> 6;
    const int lane = tid & 63;
    const int quad = lane >> 4;
    const int l16  = lane & 15;
    const int mrow = wave * 16;
    const size_t r0 = (size_t)blockIdx.x * 128;

    f32x4 acc[12] = {};
    for (int kh = 0; kh < 2; ++kh) {
        if (kh) __syncthreads();          // previous half's readers done
        // stage weight K-half: 192 rows x 192 cols bf16
        #pragma unroll
        for (int i = 0; i < 9; ++i) {
            int f = tid + i * 512;        // 0..4607 (= 192*24)
            int row = f / 24;
            int c8 = (f - row * 24) * 8;
            *(uint4*)&bwh[row][c8] = *(const uint4*)&wproj_t[row * 384 + kh * 192 + c8];
        }
        __syncthreads();

        // A-fragments for this wave's 16 rows, this K-half (bf16 direct)
        bf16x8 a[6];
        #pragma unroll
        for (int ks = 0; ks < 6; ++ks)
            a[ks] = *(const bf16x8*)&concat[(r0 + mrow + l16) * 384 + kh * 192 + ks * 32 + quad * 8];
        #pragma unroll
        for (int ks = 0; ks < 6; ++ks) {
            const int k0 = ks * 32 + quad * 8;
            #pragma unroll
            for (int nt = 0; nt < 12; ++nt) {
                bf16x8 bb = *(const bf16x8*)&bwh[nt * 16 + l16][k0];
                acc[nt] = MFMA(a[ks], bb, acc[nt]);
            }
        }
    }
    #pragma unroll
    for (int nt = 0; nt < 12; ++nt) {
        const int c = nt * 16 + l16;
        const float bias = b_proj[c];
        #pragma unroll
        for (int r = 0; r < 4; ++r) {
            int row = mrow + quad * 4 + r;
            out[(r0 + row) * 192 + c] = acc[nt][r] + bias;
        }
    }
}

// ---------------------------------------------------------------------------
extern "C" void kernel_launch(void* const* d_in, const int* in_sizes, int n_in,
                              void* d_out, int out_size, void* d_ws, size_t ws_size,
                              hipStream_t stream) {
    const float* x       = (const float*)d_in[0];
    const float* mask    = (const float*)d_in[1];
    const float* w_qkv   = (const float*)d_in[2];
    const float* w_qkvm  = (const float*)d_in[3];
    const float* w_proj  = (const float*)d_in[4];
    const float* b_proj  = (const float*)d_in[5];
    const float* rpb     = (const float*)d_in[6];
    const float* pos_b   = (const float*)d_in[7];
    const int*   rel_idx = (const int*)d_in[8];

    if (ws_size < WS_NEEDED) return;

    char*   ws     = (char*)d_ws;
    __bf16* concat = (__bf16*)d_out;   // 131072*384 bf16 == out bytes, exact fit
    float*  out    = (float*)d_out;

    prep_kernel<<<1104, 256, 0, stream>>>(w_qkv, w_qkvm, w_proj, rpb, rel_idx, ws);
    attn_kernel<<<2048, 512, 0, stream>>>(x, mask, pos_b, ws, concat);
    proj_kernel<<<1024, 512, 0, stream>>>(concat, ws, b_proj, out);
}

// Round 4
// 754.043 us; speedup vs baseline: 1.5306x; 1.0053x over previous
//
#include <hip/hip_runtime.h>
#include <hip/hip_bf16.h>
#include <math.h>

// ---------------------------------------------------------------------------
// WindowAttention (self + mutual), MI355X / gfx950.
// R4: serial-chain + write-amplification attack. Skip-max softmax (bounded
// args), exp2 with log2e folded into prep tables, batched P-staging (2 RAW
// stalls/head), register-buffered output with coalesced uint4 stores, proj
// with 4-chunk K-staging at 4 blocks/CU.
// ---------------------------------------------------------------------------

#define SCALE_F 0.17677669529663687f   // 32^-0.5
#define LOG2E_F 1.4426950408889634f

// ws layout (bytes)
#define WS_WQKV_T   0u        // [576][192] bf16 (W^T: [col][k]; Q-cols ×SCALE×LOG2E)
#define WS_WQKVM_T  221184u   // [576][192] bf16
#define WS_WPROJ_T  442368u   // [192 n][384 k] bf16
#define WS_RPBG     589824u   // [6][128][128] bf16 (gathered, ×LOG2E)
#define WS_NEEDED   786432u

typedef __bf16 bf16x8 __attribute__((ext_vector_type(8)));
typedef __bf16 bf16x4 __attribute__((ext_vector_type(4)));
typedef float  f32x4  __attribute__((ext_vector_type(4)));

#define MFMA(a, b, c) __builtin_amdgcn_mfma_f32_16x16x32_bf16((a), (b), (c), 0, 0, 0)

#if __has_builtin(__builtin_amdgcn_exp2f)
#define EXP2(x) __builtin_amdgcn_exp2f(x)
#else
#define EXP2(x) exp2f(x)
#endif
#if __has_builtin(__builtin_amdgcn_rcpf)
#define RCP(x) __builtin_amdgcn_rcpf(x)
#else
#define RCP(x) (1.0f / (x))
#endif

// ---------------------------------------------------------------------------
__global__ void prep_kernel(const float* __restrict__ w_qkv,
                            const float* __restrict__ w_qkvm,
                            const float* __restrict__ w_proj,
                            const float* __restrict__ rpb_table,
                            const int*   __restrict__ rel_idx,
                            char* __restrict__ ws) {
    int idx = blockIdx.x * 256 + threadIdx.x;
    if (idx < 110592) {                       // wqkv_t / wqkvm_t: [col][k]
        int col = idx / 192, k = idx - col * 192;
        float sc = (col < 192) ? SCALE_F * LOG2E_F : 1.0f;  // Q pre-scale (exp2 form)
        ((__bf16*)(ws + WS_WQKV_T))[idx]  = (__bf16)(w_qkv[k * 576 + col] * sc);
        ((__bf16*)(ws + WS_WQKVM_T))[idx] = (__bf16)(w_qkvm[k * 576 + col] * sc);
    } else if (idx < 184320) {                // wproj_t: [n][k]
        int o = idx - 110592;
        int n = o / 384, k = o - n * 384;
        ((__bf16*)(ws + WS_WPROJ_T))[o] = (__bf16)w_proj[k * 192 + n];
    } else if (idx < 282624) {                // rpbg[h][i][j] bf16, ×LOG2E
        int o = idx - 184320;
        int h = o / 16384, r = o - h * 16384;
        ((__bf16*)(ws + WS_RPBG))[o] = (__bf16)(rpb_table[rel_idx[r] * 6 + h] * LOG2E_F);
    }
}

// ---------------------------------------------------------------------------
// Block = (window, branch). 512 threads = 8 waves; wave w owns query rows
// [16w, 16w+16). MFMA 16x16x32 bf16 layouts (HW-verified):
//   A[m = lane&15][k = quad*8 + j]; B[k = quad*8 + j][n = lane&15]
//   D: col = lane&15, row = quad*4 + reg
// LDS (79,360 B -> 2 blocks/CU):
//   kh3  [128][104] @ 0       K for 3 heads (local 96 cols + pad)
//   vt3  [ 96][136] @ 26624   V^T for 3 heads [dim][token]
//   qs   [8][16][104] @ 52736 wave-private Q staging / P staging
//   outs [128][200] @ 0       output transpose buffer (overlays kh3+vt3,
//                             used only after the final group barrier)
__global__ __launch_bounds__(512, 4)
void attn_kernel(const float* __restrict__ x,
                 const float* __restrict__ mask,
                 const float* __restrict__ pos_bias,
                 const char*  __restrict__ ws,
                 __bf16* __restrict__ concat) {
    __shared__ alignas(16) char smem[79360];
    __bf16 (*kh3)[104]     = (__bf16(*)[104])smem;
    __bf16 (*vt3)[136]     = (__bf16(*)[136])(smem + 26624);
    __bf16 (*qs)[16][104]  = (__bf16(*)[16][104])(smem + 52736);
    __bf16 (*outs)[200]    = (__bf16(*)[200])smem;

    const int b      = blockIdx.x >> 1;
    const int branch = blockIdx.x & 1;
    const int wm     = b & 63;
    const int tid    = threadIdx.x;
    const int wave   = tid >> 6;
    const int lane   = tid & 63;
    const int quad   = lane >> 4;
    const int l16    = lane & 15;
    const int mrow   = wave * 16;

    const __bf16* wt   = (const __bf16*)(ws + (branch ? WS_WQKVM_T : WS_WQKV_T));
    const __bf16* rpbg = (const __bf16*)(ws + WS_RPBG);

    // ---- x rows for this wave -> A-fragments in registers (reused 6x) ----
    bf16x8 afrag[6];
    {
        const float* xr = x + (size_t)b * 24576 + (mrow + l16) * 192;
        const float* pr = pos_bias + ((mrow + l16) & 63) * 192;
        #pragma unroll
        for (int ks = 0; ks < 6; ++ks) {
            const int k0 = ks * 32 + quad * 8;
            float4 v0 = *(const float4*)(xr + k0);
            float4 v1 = *(const float4*)(xr + k0 + 4);
            if (branch) {
                float4 p0 = *(const float4*)(pr + k0);
                float4 p1 = *(const float4*)(pr + k0 + 4);
                v0.x += p0.x; v0.y += p0.y; v0.z += p0.z; v0.w += p0.w;
                v1.x += p1.x; v1.y += p1.y; v1.z += p1.z; v1.w += p1.w;
            }
            bf16x8 f;
            f[0] = (__bf16)v0.x; f[1] = (__bf16)v0.y;
            f[2] = (__bf16)v0.z; f[3] = (__bf16)v0.w;
            f[4] = (__bf16)v1.x; f[5] = (__bf16)v1.y;
            f[6] = (__bf16)v1.z; f[7] = (__bf16)v1.w;
            afrag[ks] = f;
        }
    }

    unsigned ob[6][4];   // packed bf16 pair (col l16, col l16+16) per head per r

    #pragma unroll
    for (int g = 0; g < 2; ++g) {
        const int hc = g * 96;

        // ---- K (3 heads) -> kh3 [token][dim] ----
        {
            f32x4 acc[6] = {};
            #pragma unroll
            for (int ks = 0; ks < 6; ++ks) {
                const int k0 = ks * 32 + quad * 8;
                #pragma unroll
                for (int nt = 0; nt < 6; ++nt) {
                    bf16x8 bb = *(const bf16x8*)&wt[(192 + hc + nt * 16 + l16) * 192 + k0];
                    acc[nt] = MFMA(afrag[ks], bb, acc[nt]);
                }
            }
            #pragma unroll
            for (int nt = 0; nt < 6; ++nt)
                #pragma unroll
                for (int r = 0; r < 4; ++r)
                    kh3[mrow + quad * 4 + r][nt * 16 + l16] = (__bf16)acc[nt][r];
        }
        // ---- V (3 heads) -> vt3 [dim][token], packed b64 writes ----
        {
            f32x4 acc[6] = {};
            #pragma unroll
            for (int ks = 0; ks < 6; ++ks) {
                const int k0 = ks * 32 + quad * 8;
                #pragma unroll
                for (int nt = 0; nt < 6; ++nt) {
                    bf16x8 bb = *(const bf16x8*)&wt[(384 + hc + nt * 16 + l16) * 192 + k0];
                    acc[nt] = MFMA(afrag[ks], bb, acc[nt]);
                }
            }
            #pragma unroll
            for (int nt = 0; nt < 6; ++nt) {
                bf16x4 pv;
                #pragma unroll
                for (int r = 0; r < 4; ++r) pv[r] = (__bf16)acc[nt][r];
                *(bf16x4*)&vt3[nt * 16 + l16][mrow + quad * 4] = pv;
            }
        }
        // ---- Q (3 heads, pre-scaled) -> wave-private qs -> registers ----
        bf16x8 aq[3];
        {
            f32x4 acc[6] = {};
            #pragma unroll
            for (int ks = 0; ks < 6; ++ks) {
                const int k0 = ks * 32 + quad * 8;
                #pragma unroll
                for (int nt = 0; nt < 6; ++nt) {
                    bf16x8 bb = *(const bf16x8*)&wt[(hc + nt * 16 + l16) * 192 + k0];
                    acc[nt] = MFMA(afrag[ks], bb, acc[nt]);
                }
            }
            #pragma unroll
            for (int nt = 0; nt < 6; ++nt)
                #pragma unroll
                for (int r = 0; r < 4; ++r)
                    qs[wave][quad * 4 + r][nt * 16 + l16] = (__bf16)acc[nt][r];
            #pragma unroll
            for (int hl = 0; hl < 3; ++hl)
                aq[hl] = *(const bf16x8*)&qs[wave][l16][hl * 32 + quad * 8];
        }
        __syncthreads();    // K/V visible; Q private in regs

        __bf16 (*spw)[104] = qs[wave];   // Q slot dead -> P staging

        if (branch == 0) {
            #pragma unroll
            for (int hl = 0; hl < 3; ++hl) {
                const int h = g * 3 + hl;
                f32x4 s[8];
                #pragma unroll
                for (int ct = 0; ct < 8; ++ct) {
                    bf16x8 bk = *(const bf16x8*)&kh3[ct * 16 + l16][hl * 32 + quad * 8];
                    f32x4 z = {};
                    s[ct] = MFMA(aq[hl], bk, z);
                }
                // skip-max softmax (args bounded; exp2 form, log2e pre-folded)
                float rl[4];
                #pragma unroll
                for (int r = 0; r < 4; ++r) {
                    const int i = mrow + quad * 4 + r;
                    const __bf16* rb = rpbg + (h * 128 + i) * 128 + l16;
                    const float*  mk = mask + ((size_t)wm * 128 + i) * 128 + l16;
                    float sum = 0.f;
                    #pragma unroll
                    for (int ct = 0; ct < 8; ++ct) {
                        float bias = fmaf(mk[ct * 16], LOG2E_F, (float)rb[ct * 16]);
                        float p = EXP2(s[ct][r] + bias);
                        s[ct][r] = p;
                        sum += p;
                    }
                    #pragma unroll
                    for (int off = 1; off < 16; off <<= 1)
                        sum += __shfl_xor(sum, off, 64);
                    rl[r] = RCP(sum);
                }
                // PV: two 64-key batches, one RAW stall each
                f32x4 o[2] = {};
                #pragma unroll
                for (int kb2 = 0; kb2 < 2; ++kb2) {
                    #pragma unroll
                    for (int ct = 0; ct < 4; ++ct)
                        #pragma unroll
                        for (int r = 0; r < 4; ++r)
                            spw[quad * 4 + r][ct * 16 + l16] = (__bf16)s[kb2 * 4 + ct][r];
                    #pragma unroll
                    for (int kb = 0; kb < 2; ++kb) {
                        const int k0l = kb * 32 + quad * 8;
                        bf16x8 p = *(const bf16x8*)&spw[l16][k0l];
                        #pragma unroll
                        for (int nt = 0; nt < 2; ++nt) {
                            bf16x8 bv = *(const bf16x8*)
                                &vt3[hl * 32 + nt * 16 + l16][kb2 * 64 + k0l];
                            o[nt] = MFMA(p, bv, o[nt]);
                        }
                    }
                }
                #pragma unroll
                for (int r = 0; r < 4; ++r) {
                    union { __bf16 hh[2]; unsigned u; } pk;
                    pk.hh[0] = (__bf16)(o[0][r] * rl[r]);
                    pk.hh[1] = (__bf16)(o[1][r] * rl[r]);
                    ob[h][r] = pk.u;
                }
            }
        } else {
            const int kbase = (mrow < 64) ? 64 : 0;
            #pragma unroll
            for (int hl = 0; hl < 3; ++hl) {
                const int h = g * 3 + hl;
                f32x4 s[4];
                #pragma unroll
                for (int ct = 0; ct < 4; ++ct) {
                    bf16x8 bk = *(const bf16x8*)&kh3[kbase + ct * 16 + l16][hl * 32 + quad * 8];
                    f32x4 z = {};
                    s[ct] = MFMA(aq[hl], bk, z);
                }
                float rl[4];
                #pragma unroll
                for (int r = 0; r < 4; ++r) {
                    const int i = mrow + quad * 4 + r;
                    const float* mk = mask + ((size_t)wm * 128 + (i & 63)) * 128 + l16;
                    float sum = 0.f;
                    #pragma unroll
                    for (int ct = 0; ct < 4; ++ct) {
                        float p = EXP2(fmaf(mk[ct * 16], LOG2E_F, s[ct][r]));
                        s[ct][r] = p;
                        sum += p;
                    }
                    #pragma unroll
                    for (int off = 1; off < 16; off <<= 1)
                        sum += __shfl_xor(sum, off, 64);
                    rl[r] = RCP(sum);
                }
                #pragma unroll
                for (int ct = 0; ct < 4; ++ct)
                    #pragma unroll
                    for (int r = 0; r < 4; ++r)
                        spw[quad * 4 + r][ct * 16 + l16] = (__bf16)s[ct][r];
                f32x4 o[2] = {};
                #pragma unroll
                for (int kb = 0; kb < 2; ++kb) {
                    const int k0l = kb * 32 + quad * 8;
                    bf16x8 p = *(const bf16x8*)&spw[l16][k0l];
                    #pragma unroll
                    for (int nt = 0; nt < 2; ++nt) {
                        bf16x8 bv = *(const bf16x8*)
                            &vt3[hl * 32 + nt * 16 + l16][kbase + k0l];
                        o[nt] = MFMA(p, bv, o[nt]);
                    }
                }
                #pragma unroll
                for (int r = 0; r < 4; ++r) {
                    union { __bf16 hh[2]; unsigned u; } pk;
                    pk.hh[0] = (__bf16)(o[0][r] * rl[r]);
                    pk.hh[1] = (__bf16)(o[1][r] * rl[r]);
                    ob[h][r] = pk.u;
                }
            }
        }
        __syncthreads();    // kh3/vt3 readers done before next group / outs
    }

    // ---- output: regs -> LDS transpose -> coalesced uint4 global stores ----
    #pragma unroll
    for (int h = 0; h < 6; ++h)
        #pragma unroll
        for (int r = 0; r < 4; ++r) {
            const int i = mrow + quad * 4 + r;
            const int row = branch ? ((i + 64) & 127) : i;   // mutual token rotation
            union { unsigned u; __bf16 hh[2]; } pk;
            pk.u = ob[h][r];
            outs[row][h * 32 + l16]      = pk.hh[0];
            outs[row][h * 32 + 16 + l16] = pk.hh[1];
        }
    __syncthreads();
    {
        const int colofs = branch ? 0 : 192;
        #pragma unroll
        for (int i = 0; i < 6; ++i) {
            int f = tid + i * 512;            // 0..3071 (128 rows x 24 uint4)
            int row = f / 24;
            int c8 = (f - row * 24) * 8;
            *(uint4*)&concat[((size_t)b * 128 + row) * 384 + colofs + c8] =
                *(const uint4*)&outs[row][c8];
        }
    }
}

// ---------------------------------------------------------------------------
// out = concat @ w_proj + b_proj. 64 rows/block, 256 thr (4 waves x 16 rows),
// weights staged in four 96-K chunks (38.4 KB LDS -> 4 blocks/CU). A-frags
// hoisted before first barrier. concat aliases d_out: rows block-exclusive,
// reads complete (in-wave) before epilogue stores.
__global__ __launch_bounds__(256, 4)
void proj_kernel(const __bf16* __restrict__ concat,
                 const char* __restrict__ ws,
                 const float* __restrict__ b_proj,
                 float* __restrict__ out) {
    __shared__ alignas(16) __bf16 bw[192][100];
    const __bf16* wp = (const __bf16*)(ws + WS_WPROJ_T);
    const int tid  = threadIdx.x;
    const int wave = tid >> 6;
    const int lane = tid & 63;
    const int quad = lane >> 4;
    const int l16  = lane & 15;
    const int mrow = wave * 16;
    const size_t r0 = (size_t)blockIdx.x * 64;

    bf16x8 a[12];
    {
        const __bf16* arow = concat + (r0 + mrow + l16) * 384;
        #pragma unroll
        for (int ks = 0; ks < 12; ++ks)
            a[ks] = *(const bf16x8*)&arow[ks * 32 + quad * 8];
    }
    f32x4 acc[12] = {};
    for (int c = 0; c < 4; ++c) {
        if (c) __syncthreads();
        #pragma unroll
        for (int i = 0; i < 9; ++i) {
            int f = tid + i * 256;            // 0..2303 (192 rows x 12 uint4)
            int row = f / 12;
            int cc = (f - row * 12) * 8;
            *(uint4*)&bw[row][cc] = *(const uint4*)&wp[row * 384 + c * 96 + cc];
        }
        __syncthreads();
        #pragma unroll
        for (int k3 = 0; k3 < 3; ++k3) {
            const int k0 = k3 * 32 + quad * 8;
            bf16x8 af = a[c * 3 + k3];
            #pragma unroll
            for (int nt = 0; nt < 12; ++nt) {
                bf16x8 bb = *(const bf16x8*)&bw[nt * 16 + l16][k0];
                acc[nt] = MFMA(af, bb, acc[nt]);
            }
        }
    }
    #pragma unroll
    for (int nt = 0; nt < 12; ++nt) {
        const int cc = nt * 16 + l16;
        const float bias = b_proj[cc];
        #pragma unroll
        for (int r = 0; r < 4; ++r)
            out[(r0 + mrow + quad * 4 + r) * 192 + cc] = acc[nt][r] + bias;
    }
}

// ---------------------------------------------------------------------------
extern "C" void kernel_launch(void* const* d_in, const int* in_sizes, int n_in,
                              void* d_out, int out_size, void* d_ws, size_t ws_size,
                              hipStream_t stream) {
    const float* x       = (const float*)d_in[0];
    const float* mask    = (const float*)d_in[1];
    const float* w_qkv   = (const float*)d_in[2];
    const float* w_qkvm  = (const float*)d_in[3];
    const float* w_proj  = (const float*)d_in[4];
    const float* b_proj  = (const float*)d_in[5];
    const float* rpb     = (const float*)d_in[6];
    const float* pos_b   = (const float*)d_in[7];
    const int*   rel_idx = (const int*)d_in[8];

    if (ws_size < WS_NEEDED) return;

    char*   ws     = (char*)d_ws;
    __bf16* concat = (__bf16*)d_out;   // 131072*384 bf16 == out bytes, exact fit
    float*  out    = (float*)d_out;

    prep_kernel<<<1104, 256, 0, stream>>>(w_qkv, w_qkvm, w_proj, rpb, rel_idx, ws);
    attn_kernel<<<2048, 512, 0, stream>>>(x, mask, pos_b, ws, concat);
    proj_kernel<<<2048, 256, 0, stream>>>(concat, ws, b_proj, out);
}